// Round 5
// baseline (532.363 us; speedup 1.0000x reference)
//
#include <hip/hip_runtime.h>
#include <hip/hip_bf16.h>
#include <math.h>

#define NROWS 8192
#define EMB   300
#define KPAD  320   // padded feature/K dim (multiple of 64)
#define NCLS  128
#define TINV  10.0f // 1/TEMP

typedef __attribute__((ext_vector_type(8))) short short8;
typedef __attribute__((ext_vector_type(4))) float f32x4;

__device__ __forceinline__ void split_bf16(float v, short& hi, short& lo)
{
  __hip_bfloat16 h = __float2bfloat16(v);
  __hip_bfloat16 l = __float2bfloat16(v - __bfloat162float(h));
  hi = *(short*)&h;
  lo = *(short*)&l;
}

// ---------------------------------------------------------------------------
// Cast input X [8192 x 300] f32 -> split bf16 planes Xh/Xl [8192 x 320].
// ---------------------------------------------------------------------------
__global__ __launch_bounds__(320)
void conv_x(const float* __restrict__ X, short* __restrict__ Xh,
            short* __restrict__ Xl)
{
  int r = blockIdx.x, c = threadIdx.x;
  float v = (c < EMB) ? X[(size_t)r * EMB + c] : 0.f;
  short h, l;
  split_bf16(v, h, l);
  Xh[(size_t)r * KPAD + c] = h;
  Xl[(size_t)r * KPAD + c] = l;
}

// ---------------------------------------------------------------------------
// Transpose+cast W [300 x 300] f32 (k-major) -> split bf16 planes Wh/Wl
// [320 x 320] n-major (row n holds contiguous k). Pads = 0.
// ---------------------------------------------------------------------------
__global__ __launch_bounds__(320)
void conv_wt(const float* __restrict__ W, short* __restrict__ Wh,
             short* __restrict__ Wl)
{
  int n = blockIdx.x, k = threadIdx.x;
  float v = (n < EMB && k < EMB) ? W[(size_t)k * EMB + n] : 0.f;
  short h, l;
  split_bf16(v, h, l);
  Wh[(size_t)n * KPAD + k] = h;
  Wl[(size_t)n * KPAD + k] = l;
}

// ---------------------------------------------------------------------------
// Split-bf16 MFMA GEMM (fp32-quality): C = act(A @ Bt^T + bias) with
//   A ~ Ah+Al, B ~ Bh+Bl,  acc = Ah Bh + Ah Bl + Al Bh   (Markidis).
// Block = 4 waves stacked in M: tile 256x64; wave tile 64x64 as 4x4 frags of
// mfma_f32_16x16x32_bf16. OUTSPLIT writes split-bf16 planes, else fp32.
// C/D layout: col = lane&15, row = (lane>>4)*4 + reg  [m89/m91].
// ---------------------------------------------------------------------------
template<int RELU, int OUTSPLIT>
__global__ __launch_bounds__(256)
void gemm_mfma3(const short* __restrict__ Ah, const short* __restrict__ Al,
                const short* __restrict__ Bh, const short* __restrict__ Bl,
                const float* __restrict__ bias,
                float* __restrict__ Cf, short* __restrict__ Ch,
                short* __restrict__ Cl)
{
  const int lane = threadIdx.x & 63;
  const int w    = threadIdx.x >> 6;
  const int i0   = blockIdx.x * 256 + w * 64;
  const int j0   = blockIdx.y * 64;
  const int rrow = lane & 15;
  const int kgrp = (lane >> 4) * 8;
  const int jc   = lane & 15;
  const int rq   = (lane >> 4) * 4;

  f32x4 acc[4][4] = {};
  for (int kk = 0; kk < KPAD; kk += 32) {
    short8 ah[4], al[4], bh[4], bl[4];
    #pragma unroll
    for (int m = 0; m < 4; ++m) {
      size_t off = (size_t)(i0 + m * 16 + rrow) * KPAD + kk + kgrp;
      ah[m] = *(const short8*)(Ah + off);
      al[m] = *(const short8*)(Al + off);
    }
    #pragma unroll
    for (int n = 0; n < 4; ++n) {
      size_t off = (size_t)(j0 + n * 16 + rrow) * KPAD + kk + kgrp;
      bh[n] = *(const short8*)(Bh + off);
      bl[n] = *(const short8*)(Bl + off);
    }
    #pragma unroll
    for (int m = 0; m < 4; ++m)
      #pragma unroll
      for (int n = 0; n < 4; ++n) {
        acc[m][n] = __builtin_amdgcn_mfma_f32_16x16x32_bf16(ah[m], bh[n], acc[m][n], 0, 0, 0);
        acc[m][n] = __builtin_amdgcn_mfma_f32_16x16x32_bf16(ah[m], bl[n], acc[m][n], 0, 0, 0);
        acc[m][n] = __builtin_amdgcn_mfma_f32_16x16x32_bf16(al[m], bh[n], acc[m][n], 0, 0, 0);
      }
  }

  #pragma unroll
  for (int n = 0; n < 4; ++n) {
    int j = j0 + n * 16 + jc;
    float bb = (j < EMB) ? bias[j] : 0.f;
    #pragma unroll
    for (int m = 0; m < 4; ++m) {
      int ibase = i0 + m * 16 + rq;
      #pragma unroll
      for (int r = 0; r < 4; ++r) {
        float v = acc[m][n][r] + bb;
        if (RELU) v = fmaxf(v, 0.f);
        size_t off = (size_t)(ibase + r) * KPAD + j;
        if (OUTSPLIT) { short h, l; split_bf16(v, h, l); Ch[off] = h; Cl[off] = l; }
        else          { Cf[off] = v; }
      }
    }
  }
}

// ---------------------------------------------------------------------------
// Per-row L2 normalize (in place, fp32), bf16 copy for Gram, class counts.
// ---------------------------------------------------------------------------
__global__ __launch_bounds__(256)
void normalize_count(float* __restrict__ H, __hip_bfloat16* __restrict__ FB,
                     const int* __restrict__ labels, int* __restrict__ cnt)
{
  int wid = threadIdx.x >> 6, lane = threadIdx.x & 63;
  int r = blockIdx.x * 4 + wid;
  float* row = H + (size_t)r * KPAD;
  __hip_bfloat16* rb = FB + (size_t)r * KPAD;
  float v[5];
  float ss = 0.f;
  #pragma unroll
  for (int q = 0; q < 5; ++q) {
    v[q] = row[lane + 64 * q];
    ss = fmaf(v[q], v[q], ss);
  }
  #pragma unroll
  for (int off = 32; off; off >>= 1) ss += __shfl_xor(ss, off);
  float inv = 1.0f / fmaxf(sqrtf(ss), 1e-12f);
  #pragma unroll
  for (int q = 0; q < 5; ++q) {
    float nv = v[q] * inv;
    row[lane + 64 * q] = nv;
    rb[lane + 64 * q] = __float2bfloat16(nv);
  }
  if (lane == 0) atomicAdd(&cnt[labels[r]], 1);
}

// ---------------------------------------------------------------------------
// Per-class feature sums: chunked gather (grid = chunks x classes), fp32.
// ---------------------------------------------------------------------------
#define CSCHUNK 1024
__global__ __launch_bounds__(320)
void class_sum_gather(const float* __restrict__ F, const int* __restrict__ labels,
                      float* __restrict__ cs)
{
  int c = blockIdx.y;
  int r0 = blockIdx.x * CSCHUNK;
  int d = threadIdx.x;
  float s = 0.f;
  for (int r = r0; r < r0 + CSCHUNK; ++r)
    if (labels[r] == c) s += F[(size_t)r * KPAD + d];
  atomicAdd(&cs[(size_t)c * KPAD + d], s);
}

// ---------------------------------------------------------------------------
// Symmetric MFMA Gram + exp + row/col sums.
//   S[i] = sum_{j != i} exp((f_i . f_j - 1) * 10)
// Upper-triangular 128x128 tiles (jt >= it); off-diag tiles also commit exp
// col-sums to S[j-range] (G symmetric). Diag tiles: row-sums only (self
// masked). 4 waves (2x2), wave tile 64x64; fragments direct from global
// (F bf16 = 5.2 MB, LLC-resident).
// ---------------------------------------------------------------------------
__global__ __launch_bounds__(256)
void gram_s_mfma(const __hip_bfloat16* __restrict__ FBh, float* __restrict__ S)
{
  const int it = blockIdx.x, jt = blockIdx.y;
  if (jt < it) return;
  const bool offdiag = (jt > it);

  const short* FB = (const short*)FBh;
  const int lane = threadIdx.x & 63;
  const int w    = threadIdx.x >> 6;
  const int wr   = w >> 1, wc = w & 1;
  const int i0   = it * 128 + wr * 64;
  const int j0   = jt * 128 + wc * 64;
  const int rrow = lane & 15;
  const int kgrp = (lane >> 4) * 8;
  const int jc   = lane & 15;
  const int rq   = (lane >> 4) * 4;

  f32x4 acc[4][4] = {};
  for (int kk = 0; kk < KPAD; kk += 32) {
    short8 a[4], b[4];
    #pragma unroll
    for (int m = 0; m < 4; ++m)
      a[m] = *(const short8*)(FB + (size_t)(i0 + m * 16 + rrow) * KPAD + kk + kgrp);
    #pragma unroll
    for (int n = 0; n < 4; ++n)
      b[n] = *(const short8*)(FB + (size_t)(j0 + n * 16 + rrow) * KPAD + kk + kgrp);
    #pragma unroll
    for (int m = 0; m < 4; ++m)
      #pragma unroll
      for (int n = 0; n < 4; ++n)
        acc[m][n] = __builtin_amdgcn_mfma_f32_16x16x32_bf16(a[m], b[n], acc[m][n], 0, 0, 0);
  }

  float psum[4][4] = {};   // [m][reg] row partials
  float csum[4]    = {};   // [n] col partials
  #pragma unroll
  for (int m = 0; m < 4; ++m) {
    int ibase = i0 + m * 16 + rq;
    #pragma unroll
    for (int n = 0; n < 4; ++n) {
      int j = j0 + n * 16 + jc;
      #pragma unroll
      for (int r = 0; r < 4; ++r) {
        float e = __expf((acc[m][n][r] - 1.0f) * TINV);
        e = (ibase + r == j) ? 0.0f : e;
        psum[m][r] += e;
        csum[n]    += e;
      }
    }
  }
  #pragma unroll
  for (int m = 0; m < 4; ++m)
    #pragma unroll
    for (int r = 0; r < 4; ++r) {
      float s = psum[m][r];
      s += __shfl_xor(s, 1); s += __shfl_xor(s, 2);
      s += __shfl_xor(s, 4); s += __shfl_xor(s, 8);
      if (jc == 0) atomicAdd(&S[i0 + m * 16 + rq + r], s);
    }
  if (offdiag) {
    #pragma unroll
    for (int n = 0; n < 4; ++n) {
      float s = csum[n];
      s += __shfl_xor(s, 16); s += __shfl_xor(s, 32);
      if ((lane >> 4) == 0) atomicAdd(&S[j0 + n * 16 + jc], s);
    }
  }
}

// ---------------------------------------------------------------------------
// Per-row loss. mean_i = [(f_i.cs[c] - f_i.f_i) - row_pos]*10 / row_pos - log S_i
// loss = -0.1 * sum(valid mean_i) / n_valid
// ---------------------------------------------------------------------------
__global__ __launch_bounds__(256)
void loss_rows(const float* __restrict__ F, const int* __restrict__ labels,
               const int* __restrict__ cnt, const float* __restrict__ cs,
               const float* __restrict__ S, float* __restrict__ acc)
{
  int wid = threadIdx.x >> 6, lane = threadIdx.x & 63;
  int r = blockIdx.x * 4 + wid;
  int c = labels[r];
  const float* f = F + (size_t)r * KPAD;
  const float* g = cs + (size_t)c * KPAD;
  float pd = 0.f, sd = 0.f;
  #pragma unroll
  for (int q = 0; q < 5; ++q) {
    float fv = f[lane + 64 * q];
    pd = fmaf(fv, g[lane + 64 * q], pd);
    sd = fmaf(fv, fv, sd);
  }
  #pragma unroll
  for (int off = 32; off; off >>= 1) {
    pd += __shfl_xor(pd, off);
    sd += __shfl_xor(sd, off);
  }
  if (lane == 0) {
    int rp = cnt[c] - 1;
    if (rp > 0) {
      float sum_stab = (pd - sd) * TINV - TINV * (float)rp;
      float mean = sum_stab / (float)rp - logf(S[r]);
      atomicAdd(&acc[0], mean);
      atomicAdd(&acc[1], 1.0f);
    }
  }
}

__global__ void finalize(const float* __restrict__ acc, float* __restrict__ out)
{
  out[0] = -0.1f * acc[0] / fmaxf(acc[1], 1.0f);
}

// ---------------------------------------------------------------------------
extern "C" void kernel_launch(void* const* d_in, const int* in_sizes, int n_in,
                              void* d_out, int out_size, void* d_ws, size_t ws_size,
                              hipStream_t stream)
{
  const float* X      = (const float*)d_in[0];   // [8192 x 300]
  const int*   labels = (const int*)d_in[1];     // [8192]
  const float* W1     = (const float*)d_in[2];   // [300 x 300]
  const float* b1     = (const float*)d_in[3];   // [300]
  const float* W2     = (const float*)d_in[4];   // [300 x 300]
  const float* b2     = (const float*)d_in[5];   // [300]
  float* out = (float*)d_out;

  // ---- workspace layout: bf16 planes first, then f32 region ----
  const size_t NP = (size_t)NROWS * KPAD;        // rows plane elems
  const size_t WP = (size_t)KPAD * KPAD;         // weight plane elems
  short* Xh  = (short*)d_ws;
  short* Xl  = Xh + NP;
  short* Hh  = Xl + NP;
  short* Hl  = Hh + NP;
  __hip_bfloat16* fb = (__hip_bfloat16*)(Hl + NP);
  short* W1h = (short*)(fb + NP);
  short* W1l = W1h + WP;
  short* W2h = W1l + WP;
  short* W2l = W2h + WP;
  float* fpad = (float*)(W2l + WP);              // 8192*320 f32
  float* cs   = fpad + NP;                       // 128*320
  float* S    = cs + (size_t)NCLS * KPAD;        // 8192
  int*   cnt  = (int*)(S + NROWS);               // 128
  float* acc  = (float*)(cnt + NCLS);            // 2

  // zero cs, S, cnt, acc (contiguous)
  size_t zbytes = ((size_t)NCLS * KPAD + NROWS + NCLS + 2) * sizeof(float);
  hipMemsetAsync(cs, 0, zbytes, stream);

  // split-bf16 casts / transposes
  conv_x <<<NROWS, 320, 0, stream>>>(X, Xh, Xl);
  conv_wt<<<KPAD,  320, 0, stream>>>(W1, W1h, W1l);
  conv_wt<<<KPAD,  320, 0, stream>>>(W2, W2h, W2l);

  // projector (fp32-quality via 3-term split):
  //   H = relu(X @ W1 + b1) -> split planes; fpad = H @ W2 + b2 -> f32
  dim3 pg(NROWS / 256, KPAD / 64);
  gemm_mfma3<1, 1><<<pg, 256, 0, stream>>>(Xh, Xl, W1h, W1l, b1,
                                           nullptr, Hh, Hl);
  gemm_mfma3<0, 0><<<pg, 256, 0, stream>>>(Hh, Hl, W2h, W2l, b2,
                                           fpad, nullptr, nullptr);

  normalize_count<<<NROWS / 4, 256, 0, stream>>>(fpad, fb, labels, cnt);

  dim3 cg(NROWS / CSCHUNK, NCLS);
  class_sum_gather<<<cg, 320, 0, stream>>>(fpad, labels, cs);

  dim3 gs(NROWS / 128, NROWS / 128);   // upper-tri blocks do work, rest exit
  gram_s_mfma<<<gs, 256, 0, stream>>>(fb, S);

  loss_rows<<<NROWS / 4, 256, 0, stream>>>(fpad, labels, cnt, cs, S, acc);
  finalize<<<1, 1, 0, stream>>>(acc, out);
}

// Round 11
// 321.893 us; speedup vs baseline: 1.6539x; 1.6539x over previous
//
#include <hip/hip_runtime.h>
#include <hip/hip_bf16.h>
#include <math.h>

#define NROWS 8192
#define EMB   300
#define KPAD  320   // padded feature/K dim (multiple of 64)
#define NCLS  128
#define TINV  10.0f // 1/TEMP
#define LR_BLOCKS 512   // loss_rows blocks; 16 rows per block (4 waves x 4 rows)

typedef __attribute__((ext_vector_type(8))) short short8;
typedef __attribute__((ext_vector_type(4))) float f32x4;

__device__ __forceinline__ void split_bf16(float v, short& hi, short& lo)
{
  __hip_bfloat16 h = __float2bfloat16(v);
  __hip_bfloat16 l = __float2bfloat16(v - __bfloat162float(h));
  hi = *(short*)&h;
  lo = *(short*)&l;
}

// ---------------------------------------------------------------------------
// Cast input X [8192 x 300] f32 -> split bf16 planes Xh/Xl [8192 x 320].
// ---------------------------------------------------------------------------
__global__ __launch_bounds__(320)
void conv_x(const float* __restrict__ X, short* __restrict__ Xh,
            short* __restrict__ Xl)
{
  int r = blockIdx.x, c = threadIdx.x;
  float v = (c < EMB) ? X[(size_t)r * EMB + c] : 0.f;
  short h, l;
  split_bf16(v, h, l);
  Xh[(size_t)r * KPAD + c] = h;
  Xl[(size_t)r * KPAD + c] = l;
}

// ---------------------------------------------------------------------------
// Transpose+cast W [300 x 300] f32 (k-major) -> split bf16 planes Wh/Wl
// [320 x 320] n-major (row n holds contiguous k). Pads = 0.
// ---------------------------------------------------------------------------
__global__ __launch_bounds__(320)
void conv_wt(const float* __restrict__ W, short* __restrict__ Wh,
             short* __restrict__ Wl)
{
  int n = blockIdx.x, k = threadIdx.x;
  float v = (n < EMB && k < EMB) ? W[(size_t)k * EMB + n] : 0.f;
  short h, l;
  split_bf16(v, h, l);
  Wh[(size_t)n * KPAD + k] = h;
  Wl[(size_t)n * KPAD + k] = l;
}

// ---------------------------------------------------------------------------
// Split-bf16 MFMA GEMM (fp32-quality): C = act(A @ Bt^T + bias) with
//   A ~ Ah+Al, B ~ Bh+Bl,  acc = Ah Bh + Ah Bl + Al Bh   (Markidis).
// Block = 4 waves stacked in M: tile 256x64; wave tile 64x64 as 4x4 frags of
// mfma_f32_16x16x32_bf16. OUTSPLIT writes split-bf16 planes, else fp32.
// C/D layout: col = lane&15, row = (lane>>4)*4 + reg  [m89/m91].
// ---------------------------------------------------------------------------
template<int RELU, int OUTSPLIT>
__global__ __launch_bounds__(256)
void gemm_mfma3(const short* __restrict__ Ah, const short* __restrict__ Al,
                const short* __restrict__ Bh, const short* __restrict__ Bl,
                const float* __restrict__ bias,
                float* __restrict__ Cf, short* __restrict__ Ch,
                short* __restrict__ Cl)
{
  const int lane = threadIdx.x & 63;
  const int w    = threadIdx.x >> 6;
  const int i0   = blockIdx.x * 256 + w * 64;
  const int j0   = blockIdx.y * 64;
  const int rrow = lane & 15;
  const int kgrp = (lane >> 4) * 8;
  const int jc   = lane & 15;
  const int rq   = (lane >> 4) * 4;

  f32x4 acc[4][4] = {};
  for (int kk = 0; kk < KPAD; kk += 32) {
    short8 ah[4], al[4], bh[4], bl[4];
    #pragma unroll
    for (int m = 0; m < 4; ++m) {
      size_t off = (size_t)(i0 + m * 16 + rrow) * KPAD + kk + kgrp;
      ah[m] = *(const short8*)(Ah + off);
      al[m] = *(const short8*)(Al + off);
    }
    #pragma unroll
    for (int n = 0; n < 4; ++n) {
      size_t off = (size_t)(j0 + n * 16 + rrow) * KPAD + kk + kgrp;
      bh[n] = *(const short8*)(Bh + off);
      bl[n] = *(const short8*)(Bl + off);
    }
    #pragma unroll
    for (int m = 0; m < 4; ++m)
      #pragma unroll
      for (int n = 0; n < 4; ++n) {
        acc[m][n] = __builtin_amdgcn_mfma_f32_16x16x32_bf16(ah[m], bh[n], acc[m][n], 0, 0, 0);
        acc[m][n] = __builtin_amdgcn_mfma_f32_16x16x32_bf16(ah[m], bl[n], acc[m][n], 0, 0, 0);
        acc[m][n] = __builtin_amdgcn_mfma_f32_16x16x32_bf16(al[m], bh[n], acc[m][n], 0, 0, 0);
      }
  }

  #pragma unroll
  for (int n = 0; n < 4; ++n) {
    int j = j0 + n * 16 + jc;
    float bb = (j < EMB) ? bias[j] : 0.f;
    #pragma unroll
    for (int m = 0; m < 4; ++m) {
      int ibase = i0 + m * 16 + rq;
      #pragma unroll
      for (int r = 0; r < 4; ++r) {
        float v = acc[m][n][r] + bb;
        if (RELU) v = fmaxf(v, 0.f);
        size_t off = (size_t)(ibase + r) * KPAD + j;
        if (OUTSPLIT) { short h, l; split_bf16(v, h, l); Ch[off] = h; Cl[off] = l; }
        else          { Cf[off] = v; }
      }
    }
  }
}

// ---------------------------------------------------------------------------
// Per-row L2 normalize (in place, fp32), bf16 copy for Gram, class counts.
// (cnt atomics: 8192 adds over 128 addresses — fine.)
// ---------------------------------------------------------------------------
__global__ __launch_bounds__(256)
void normalize_count(float* __restrict__ H, __hip_bfloat16* __restrict__ FB,
                     const int* __restrict__ labels, int* __restrict__ cnt)
{
  int wid = threadIdx.x >> 6, lane = threadIdx.x & 63;
  int r = blockIdx.x * 4 + wid;
  float* row = H + (size_t)r * KPAD;
  __hip_bfloat16* rb = FB + (size_t)r * KPAD;
  float v[5];
  float ss = 0.f;
  #pragma unroll
  for (int q = 0; q < 5; ++q) {
    v[q] = row[lane + 64 * q];
    ss = fmaf(v[q], v[q], ss);
  }
  #pragma unroll
  for (int off = 32; off; off >>= 1) ss += __shfl_xor(ss, off);
  float inv = 1.0f / fmaxf(sqrtf(ss), 1e-12f);
  #pragma unroll
  for (int q = 0; q < 5; ++q) {
    float nv = v[q] * inv;
    row[lane + 64 * q] = nv;
    rb[lane + 64 * q] = __float2bfloat16(nv);
  }
  if (lane == 0) atomicAdd(&cnt[labels[r]], 1);
}

// ---------------------------------------------------------------------------
// Per-class feature sums: chunked gather (grid = chunks x classes), fp32.
// ---------------------------------------------------------------------------
#define CSCHUNK 1024
__global__ __launch_bounds__(320)
void class_sum_gather(const float* __restrict__ F, const int* __restrict__ labels,
                      float* __restrict__ cs)
{
  int c = blockIdx.y;
  int r0 = blockIdx.x * CSCHUNK;
  int d = threadIdx.x;
  float s = 0.f;
  for (int r = r0; r < r0 + CSCHUNK; ++r)
    if (labels[r] == c) s += F[(size_t)r * KPAD + d];
  atomicAdd(&cs[(size_t)c * KPAD + d], s);
}

// ---------------------------------------------------------------------------
// Symmetric MFMA Gram + exp + row/col sums.
//   S[i] = sum_{j != i} exp((f_i . f_j - 1) * 10)
// Upper-triangular 128x128 tiles (jt >= it); off-diag tiles also commit exp
// col-sums to S[j-range] (G symmetric). Diag tiles: row-sums only.
// S atomics: ~0.5M adds spread over 8192 addresses — low contention.
// ---------------------------------------------------------------------------
__global__ __launch_bounds__(256)
void gram_s_mfma(const __hip_bfloat16* __restrict__ FBh, float* __restrict__ S)
{
  const int it = blockIdx.x, jt = blockIdx.y;
  if (jt < it) return;
  const bool offdiag = (jt > it);

  const short* FB = (const short*)FBh;
  const int lane = threadIdx.x & 63;
  const int w    = threadIdx.x >> 6;
  const int wr   = w >> 1, wc = w & 1;
  const int i0   = it * 128 + wr * 64;
  const int j0   = jt * 128 + wc * 64;
  const int rrow = lane & 15;
  const int kgrp = (lane >> 4) * 8;
  const int jc   = lane & 15;
  const int rq   = (lane >> 4) * 4;

  f32x4 acc[4][4] = {};
  for (int kk = 0; kk < KPAD; kk += 32) {
    short8 a[4], b[4];
    #pragma unroll
    for (int m = 0; m < 4; ++m)
      a[m] = *(const short8*)(FB + (size_t)(i0 + m * 16 + rrow) * KPAD + kk + kgrp);
    #pragma unroll
    for (int n = 0; n < 4; ++n)
      b[n] = *(const short8*)(FB + (size_t)(j0 + n * 16 + rrow) * KPAD + kk + kgrp);
    #pragma unroll
    for (int m = 0; m < 4; ++m)
      #pragma unroll
      for (int n = 0; n < 4; ++n)
        acc[m][n] = __builtin_amdgcn_mfma_f32_16x16x32_bf16(a[m], b[n], acc[m][n], 0, 0, 0);
  }

  float psum[4][4] = {};   // [m][reg] row partials
  float csum[4]    = {};   // [n] col partials
  #pragma unroll
  for (int m = 0; m < 4; ++m) {
    int ibase = i0 + m * 16 + rq;
    #pragma unroll
    for (int n = 0; n < 4; ++n) {
      int j = j0 + n * 16 + jc;
      #pragma unroll
      for (int r = 0; r < 4; ++r) {
        float e = __expf((acc[m][n][r] - 1.0f) * TINV);
        e = (ibase + r == j) ? 0.0f : e;
        psum[m][r] += e;
        csum[n]    += e;
      }
    }
  }
  #pragma unroll
  for (int m = 0; m < 4; ++m)
    #pragma unroll
    for (int r = 0; r < 4; ++r) {
      float s = psum[m][r];
      s += __shfl_xor(s, 1); s += __shfl_xor(s, 2);
      s += __shfl_xor(s, 4); s += __shfl_xor(s, 8);
      if (jc == 0) atomicAdd(&S[i0 + m * 16 + rq + r], s);
    }
  if (offdiag) {
    #pragma unroll
    for (int n = 0; n < 4; ++n) {
      float s = csum[n];
      s += __shfl_xor(s, 16); s += __shfl_xor(s, 32);
      if ((lane >> 4) == 0) atomicAdd(&S[j0 + n * 16 + jc], s);
    }
  }
}

// ---------------------------------------------------------------------------
// Per-row loss -> per-block partials (NO global atomics; the old 2-address
// atomicAdd serialized 8192 waves = 212 us measured). 4 waves x 4 rows each.
// partial[2b] = sum of valid means in block b, partial[2b+1] = valid count.
// ---------------------------------------------------------------------------
__global__ __launch_bounds__(256)
void loss_rows(const float* __restrict__ F, const int* __restrict__ labels,
               const int* __restrict__ cnt, const float* __restrict__ cs,
               const float* __restrict__ S, float* __restrict__ partial)
{
  __shared__ float sm[4], sc[4];
  int wid = threadIdx.x >> 6, lane = threadIdx.x & 63;
  float wsum = 0.f, wcnt = 0.f;
  #pragma unroll
  for (int rr = 0; rr < 4; ++rr) {
    int r = (blockIdx.x * 4 + wid) * 4 + rr;
    int c = labels[r];
    const float* f = F + (size_t)r * KPAD;
    const float* g = cs + (size_t)c * KPAD;
    float pd = 0.f, sd = 0.f;
    #pragma unroll
    for (int q = 0; q < 5; ++q) {
      float fv = f[lane + 64 * q];
      pd = fmaf(fv, g[lane + 64 * q], pd);
      sd = fmaf(fv, fv, sd);
    }
    #pragma unroll
    for (int off = 32; off; off >>= 1) {
      pd += __shfl_xor(pd, off);
      sd += __shfl_xor(sd, off);
    }
    int rp = cnt[c] - 1;
    if (rp > 0) {
      float sum_stab = (pd - sd) * TINV - TINV * (float)rp;
      wsum += sum_stab / (float)rp - logf(S[r]);
      wcnt += 1.0f;
    }
  }
  if (lane == 0) { sm[wid] = wsum; sc[wid] = wcnt; }
  __syncthreads();
  if (threadIdx.x == 0) {
    partial[2 * blockIdx.x]     = sm[0] + sm[1] + sm[2] + sm[3];
    partial[2 * blockIdx.x + 1] = sc[0] + sc[1] + sc[2] + sc[3];
  }
}

// ---------------------------------------------------------------------------
// Reduce LR_BLOCKS partial pairs -> loss. One block, 256 threads.
// ---------------------------------------------------------------------------
__global__ __launch_bounds__(256)
void finalize(const float* __restrict__ partial, float* __restrict__ out)
{
  __shared__ float ssum[4], scnt[4];
  int tid = threadIdx.x, lane = tid & 63, wid = tid >> 6;
  float s = 0.f, c = 0.f;
  for (int b = tid; b < LR_BLOCKS; b += 256) {
    s += partial[2 * b];
    c += partial[2 * b + 1];
  }
  #pragma unroll
  for (int off = 32; off; off >>= 1) {
    s += __shfl_xor(s, off);
    c += __shfl_xor(c, off);
  }
  if (lane == 0) { ssum[wid] = s; scnt[wid] = c; }
  __syncthreads();
  if (tid == 0) {
    float ts = ssum[0] + ssum[1] + ssum[2] + ssum[3];
    float tc = scnt[0] + scnt[1] + scnt[2] + scnt[3];
    out[0] = -0.1f * ts / fmaxf(tc, 1.0f);
  }
}

// ---------------------------------------------------------------------------
extern "C" void kernel_launch(void* const* d_in, const int* in_sizes, int n_in,
                              void* d_out, int out_size, void* d_ws, size_t ws_size,
                              hipStream_t stream)
{
  const float* X      = (const float*)d_in[0];   // [8192 x 300]
  const int*   labels = (const int*)d_in[1];     // [8192]
  const float* W1     = (const float*)d_in[2];   // [300 x 300]
  const float* b1     = (const float*)d_in[3];   // [300]
  const float* W2     = (const float*)d_in[4];   // [300 x 300]
  const float* b2     = (const float*)d_in[5];   // [300]
  float* out = (float*)d_out;

  // ---- workspace layout: bf16 planes first, then f32 region ----
  const size_t NP = (size_t)NROWS * KPAD;        // rows plane elems
  const size_t WP = (size_t)KPAD * KPAD;         // weight plane elems
  short* Xh  = (short*)d_ws;
  short* Xl  = Xh + NP;
  short* Hh  = Xl + NP;
  short* Hl  = Hh + NP;
  __hip_bfloat16* fb = (__hip_bfloat16*)(Hl + NP);
  short* W1h = (short*)(fb + NP);
  short* W1l = W1h + WP;
  short* W2h = W1l + WP;
  short* W2l = W2h + WP;
  float* fpad = (float*)(W2l + WP);              // 8192*320 f32
  float* cs   = fpad + NP;                       // 128*320
  float* S    = cs + (size_t)NCLS * KPAD;        // 8192
  int*   cnt  = (int*)(S + NROWS);               // 128
  float* partial = (float*)(cnt + NCLS);         // 2*LR_BLOCKS

  // zero cs, S, cnt, partial (contiguous)
  size_t zbytes = ((size_t)NCLS * KPAD + NROWS + NCLS + 2 * LR_BLOCKS) * sizeof(float);
  hipMemsetAsync(cs, 0, zbytes, stream);

  // split-bf16 casts / transposes
  conv_x <<<NROWS, 320, 0, stream>>>(X, Xh, Xl);
  conv_wt<<<KPAD,  320, 0, stream>>>(W1, W1h, W1l);
  conv_wt<<<KPAD,  320, 0, stream>>>(W2, W2h, W2l);

  // projector (fp32-quality via 3-term split)
  dim3 pg(NROWS / 256, KPAD / 64);
  gemm_mfma3<1, 1><<<pg, 256, 0, stream>>>(Xh, Xl, W1h, W1l, b1,
                                           nullptr, Hh, Hl);
  gemm_mfma3<0, 0><<<pg, 256, 0, stream>>>(Hh, Hl, W2h, W2l, b2,
                                           fpad, nullptr, nullptr);

  normalize_count<<<NROWS / 4, 256, 0, stream>>>(fpad, fb, labels, cnt);

  dim3 cg(NROWS / CSCHUNK, NCLS);
  class_sum_gather<<<cg, 320, 0, stream>>>(fpad, labels, cs);

  dim3 gs(NROWS / 128, NROWS / 128);   // upper-tri blocks do work, rest exit
  gram_s_mfma<<<gs, 256, 0, stream>>>(fb, S);

  loss_rows<<<LR_BLOCKS, 256, 0, stream>>>(fpad, labels, cnt, cs, S, partial);
  finalize<<<1, 256, 0, stream>>>(partial, out);
}

// Round 15
// 254.040 us; speedup vs baseline: 2.0956x; 1.2671x over previous
//
#include <hip/hip_runtime.h>
#include <hip/hip_bf16.h>
#include <math.h>

#define NROWS 8192
#define EMB   300
#define KPAD  320   // padded feature/K dim
#define NCLS  128
#define TINV  10.0f // 1/TEMP
#define LR_BLOCKS 512
#define NKC   10    // K-chunks of 32 (KPAD/32)
#define CH    512   // shorts per packed chunk (16 rows x 32 k)

typedef __attribute__((ext_vector_type(8))) short short8;
typedef __attribute__((ext_vector_type(4))) float f32x4;

// Packed fragment layout: chunk c = rowtile*NKC + k/32 holds 16 rows x 32 k,
// ordered so lane l of a wave reads row (l&15), k-sub (l>>4)*8 as one short8:
//   offset(r, k) = (( (r>>4)*NKC + (k>>5) )*CH + (((k&31)>>3)*16 + (r&15))*8 + (k&7))
__device__ __forceinline__ size_t pk(int r, int k)
{
  return ((size_t)(r >> 4) * NKC + (k >> 5)) * CH
       + (size_t)(((k & 31) >> 3) * 16 + (r & 15)) * 8 + (k & 7);
}

__device__ __forceinline__ void split_bf16(float v, short& hi, short& lo)
{
  __hip_bfloat16 h = __float2bfloat16(v);
  __hip_bfloat16 l = __float2bfloat16(v - __bfloat162float(h));
  hi = *(short*)&h;
  lo = *(short*)&l;
}

// ---------------------------------------------------------------------------
// Cast X [8192 x 300] f32 -> packed split-bf16 planes Xh/Xl.
// ---------------------------------------------------------------------------
__global__ __launch_bounds__(320)
void conv_x(const float* __restrict__ X, short* __restrict__ Xh,
            short* __restrict__ Xl)
{
  int r = blockIdx.x, c = threadIdx.x;
  float v = (c < EMB) ? X[(size_t)r * EMB + c] : 0.f;
  short h, l;
  split_bf16(v, h, l);
  size_t o = pk(r, c);
  Xh[o] = h;
  Xl[o] = l;
}

// ---------------------------------------------------------------------------
// Transpose+cast W [300 x 300] (k-major) -> packed split planes, B-operand
// order: "row" = n (output col), "k" = k. Pads = 0.
// ---------------------------------------------------------------------------
__global__ __launch_bounds__(320)
void conv_wt(const float* __restrict__ W, short* __restrict__ Wh,
             short* __restrict__ Wl)
{
  int n = blockIdx.x, k = threadIdx.x;
  float v = (n < EMB && k < EMB) ? W[(size_t)k * EMB + n] : 0.f;
  short h, l;
  split_bf16(v, h, l);
  size_t o = pk(n, k);
  Wh[o] = h;
  Wl[o] = l;
}

#define LOADP(dst, base, rt0, kt)                                             \
  _Pragma("unroll")                                                           \
  for (int m_ = 0; m_ < 4; ++m_)                                              \
    dst[m_] = *(const short8*)((base) +                                       \
      (((size_t)(rt0) + m_) * NKC + (kt)) * CH + (size_t)lane * 8);

// ---------------------------------------------------------------------------
// Split-bf16 MFMA GEMM on packed operands (fp32-quality, Markidis 3-term).
// One wave per block, tile 64x64, grid (128, 5). Register double-buffered.
// C/D layout: col = lane&15, row = (lane>>4)*4 + reg.
// ---------------------------------------------------------------------------
template<int RELU, int OUTSPLIT>
__global__ __launch_bounds__(64)
void gemm_mfma3p(const short* __restrict__ Ahp, const short* __restrict__ Alp,
                 const short* __restrict__ Bhp, const short* __restrict__ Blp,
                 const float* __restrict__ bias,
                 float* __restrict__ Cf, short* __restrict__ Chp,
                 short* __restrict__ Clp)
{
  const int lane = threadIdx.x;
  const int i0   = blockIdx.x * 64;
  const int j0   = blockIdx.y * 64;
  const int rta  = i0 >> 4;
  const int ntb  = j0 >> 4;
  const int jc   = lane & 15;
  const int rq   = (lane >> 4) * 4;

  f32x4 acc[4][4] = {};
  short8 ah[2][4], al[2][4], bh[2][4], bl[2][4];
  LOADP(ah[0], Ahp, rta, 0); LOADP(al[0], Alp, rta, 0);
  LOADP(bh[0], Bhp, ntb, 0); LOADP(bl[0], Blp, ntb, 0);
  #pragma unroll
  for (int kt = 0; kt < NKC; ++kt) {
    const int cu = kt & 1, nx = cu ^ 1;
    if (kt < NKC - 1) {
      LOADP(ah[nx], Ahp, rta, kt + 1); LOADP(al[nx], Alp, rta, kt + 1);
      LOADP(bh[nx], Bhp, ntb, kt + 1); LOADP(bl[nx], Blp, ntb, kt + 1);
    }
    #pragma unroll
    for (int m = 0; m < 4; ++m)
      #pragma unroll
      for (int n = 0; n < 4; ++n) {
        acc[m][n] = __builtin_amdgcn_mfma_f32_16x16x32_bf16(ah[cu][m], bh[cu][n], acc[m][n], 0, 0, 0);
        acc[m][n] = __builtin_amdgcn_mfma_f32_16x16x32_bf16(ah[cu][m], bl[cu][n], acc[m][n], 0, 0, 0);
        acc[m][n] = __builtin_amdgcn_mfma_f32_16x16x32_bf16(al[cu][m], bh[cu][n], acc[m][n], 0, 0, 0);
      }
  }

  #pragma unroll
  for (int n = 0; n < 4; ++n) {
    int j = j0 + n * 16 + jc;
    float bb = (j < EMB) ? bias[j] : 0.f;
    #pragma unroll
    for (int m = 0; m < 4; ++m) {
      #pragma unroll
      for (int r = 0; r < 4; ++r) {
        int R = i0 + m * 16 + rq + r;
        float v = acc[m][n][r] + bb;
        if (RELU) v = fmaxf(v, 0.f);
        if (OUTSPLIT) {
          short h, l;
          split_bf16(v, h, l);
          size_t o = pk(R, j);
          Chp[o] = h; Clp[o] = l;
        } else {
          Cf[(size_t)R * KPAD + j] = v;
        }
      }
    }
  }
}

// ---------------------------------------------------------------------------
// Per-row L2 normalize (fpad in place, fp32), packed-bf16 copy, class counts.
// ---------------------------------------------------------------------------
__global__ __launch_bounds__(256)
void normalize_count(float* __restrict__ H, short* __restrict__ FBp,
                     const int* __restrict__ labels, int* __restrict__ cnt)
{
  int wid = threadIdx.x >> 6, lane = threadIdx.x & 63;
  int r = blockIdx.x * 4 + wid;
  float* row = H + (size_t)r * KPAD;
  float v[5];
  float ss = 0.f;
  #pragma unroll
  for (int q = 0; q < 5; ++q) {
    v[q] = row[lane + 64 * q];
    ss = fmaf(v[q], v[q], ss);
  }
  #pragma unroll
  for (int off = 32; off; off >>= 1) ss += __shfl_xor(ss, off);
  float inv = 1.0f / fmaxf(sqrtf(ss), 1e-12f);
  #pragma unroll
  for (int q = 0; q < 5; ++q) {
    float nv = v[q] * inv;
    row[lane + 64 * q] = nv;
    __hip_bfloat16 b = __float2bfloat16(nv);
    FBp[pk(r, lane + 64 * q)] = *(short*)&b;
  }
  if (lane == 0) atomicAdd(&cnt[labels[r]], 1);
}

// ---------------------------------------------------------------------------
// Per-class feature sums: chunked gather, fp32.
// ---------------------------------------------------------------------------
#define CSCHUNK 1024
__global__ __launch_bounds__(320)
void class_sum_gather(const float* __restrict__ F, const int* __restrict__ labels,
                      float* __restrict__ cs)
{
  int c = blockIdx.y;
  int r0 = blockIdx.x * CSCHUNK;
  int d = threadIdx.x;
  float s = 0.f;
  for (int r = r0; r < r0 + CSCHUNK; ++r)
    if (labels[r] == c) s += F[(size_t)r * KPAD + d];
  atomicAdd(&cs[(size_t)c * KPAD + d], s);
}

// ---------------------------------------------------------------------------
// Symmetric MFMA Gram + exp + row/col sums, packed operands, triangular grid.
//   S[i] = sum_{j != i} exp((f_i . f_j - 1) * 10)
// 2080 blocks (jt>=it only). 4 waves (2x2), wave tile 64x64, double-buffered
// contiguous 1KB fragment loads (was: 640B-strided scatter = latency-bound,
// MfmaUtil 6.8% measured r11).
// ---------------------------------------------------------------------------
__global__ __launch_bounds__(256)
void gram_s_mfma(const short* __restrict__ FP, float* __restrict__ S)
{
  // decode linear block -> upper-tri (it, jt); verified b=0,63,64,2079
  int b = blockIdx.x;
  int it = (int)((129.0f - sqrtf(16641.0f - 8.0f * (float)b)) * 0.5f);
  int base = 64 * it - (it * (it - 1)) / 2;
  if (b < base) { --it; base = 64 * it - (it * (it - 1)) / 2; }
  else { int nb = base + (64 - it); if (b >= nb) { ++it; base = nb; } }
  const int jt = it + (b - base);
  const bool offdiag = (jt > it);

  const int lane = threadIdx.x & 63;
  const int w    = threadIdx.x >> 6;
  const int wr   = w >> 1, wc = w & 1;
  const int i0   = it * 128 + wr * 64;
  const int j0   = jt * 128 + wc * 64;
  const int rta  = i0 >> 4;
  const int rtb  = j0 >> 4;
  const int jc   = lane & 15;
  const int rq   = (lane >> 4) * 4;

  f32x4 acc[4][4] = {};
  short8 ab[2][4], bb_[2][4];
  LOADP(ab[0], FP, rta, 0); LOADP(bb_[0], FP, rtb, 0);
  #pragma unroll
  for (int kt = 0; kt < NKC; ++kt) {
    const int cu = kt & 1, nx = cu ^ 1;
    if (kt < NKC - 1) {
      LOADP(ab[nx], FP, rta, kt + 1); LOADP(bb_[nx], FP, rtb, kt + 1);
    }
    #pragma unroll
    for (int m = 0; m < 4; ++m)
      #pragma unroll
      for (int n = 0; n < 4; ++n)
        acc[m][n] = __builtin_amdgcn_mfma_f32_16x16x32_bf16(ab[cu][m], bb_[cu][n], acc[m][n], 0, 0, 0);
  }

  float psum[4][4] = {};   // [m][reg] row partials
  float csum[4]    = {};   // [n] col partials
  #pragma unroll
  for (int m = 0; m < 4; ++m) {
    int ibase = i0 + m * 16 + rq;
    #pragma unroll
    for (int n = 0; n < 4; ++n) {
      int j = j0 + n * 16 + jc;
      #pragma unroll
      for (int r = 0; r < 4; ++r) {
        float e = __expf((acc[m][n][r] - 1.0f) * TINV);
        e = (ibase + r == j) ? 0.0f : e;
        psum[m][r] += e;
        csum[n]    += e;
      }
    }
  }
  #pragma unroll
  for (int m = 0; m < 4; ++m)
    #pragma unroll
    for (int r = 0; r < 4; ++r) {
      float s = psum[m][r];
      s += __shfl_xor(s, 1); s += __shfl_xor(s, 2);
      s += __shfl_xor(s, 4); s += __shfl_xor(s, 8);
      if (jc == 0) atomicAdd(&S[i0 + m * 16 + rq + r], s);
    }
  if (offdiag) {
    #pragma unroll
    for (int n = 0; n < 4; ++n) {
      float s = csum[n];
      s += __shfl_xor(s, 16); s += __shfl_xor(s, 32);
      if ((lane >> 4) == 0) atomicAdd(&S[j0 + n * 16 + jc], s);
    }
  }
}

// ---------------------------------------------------------------------------
// Per-row loss -> per-block partials (no global atomics).
// ---------------------------------------------------------------------------
__global__ __launch_bounds__(256)
void loss_rows(const float* __restrict__ F, const int* __restrict__ labels,
               const int* __restrict__ cnt, const float* __restrict__ cs,
               const float* __restrict__ S, float* __restrict__ partial)
{
  __shared__ float sm[4], sc[4];
  int wid = threadIdx.x >> 6, lane = threadIdx.x & 63;
  float wsum = 0.f, wcnt = 0.f;
  #pragma unroll
  for (int rr = 0; rr < 4; ++rr) {
    int r = (blockIdx.x * 4 + wid) * 4 + rr;
    int c = labels[r];
    const float* f = F + (size_t)r * KPAD;
    const float* g = cs + (size_t)c * KPAD;
    float pd = 0.f, sd = 0.f;
    #pragma unroll
    for (int q = 0; q < 5; ++q) {
      float fv = f[lane + 64 * q];
      pd = fmaf(fv, g[lane + 64 * q], pd);
      sd = fmaf(fv, fv, sd);
    }
    #pragma unroll
    for (int off = 32; off; off >>= 1) {
      pd += __shfl_xor(pd, off);
      sd += __shfl_xor(sd, off);
    }
    int rp = cnt[c] - 1;
    if (rp > 0) {
      float sum_stab = (pd - sd) * TINV - TINV * (float)rp;
      wsum += sum_stab / (float)rp - logf(S[r]);
      wcnt += 1.0f;
    }
  }
  if (lane == 0) { sm[wid] = wsum; sc[wid] = wcnt; }
  __syncthreads();
  if (threadIdx.x == 0) {
    partial[2 * blockIdx.x]     = sm[0] + sm[1] + sm[2] + sm[3];
    partial[2 * blockIdx.x + 1] = sc[0] + sc[1] + sc[2] + sc[3];
  }
}

__global__ __launch_bounds__(256)
void finalize(const float* __restrict__ partial, float* __restrict__ out)
{
  __shared__ float ssum[4], scnt[4];
  int tid = threadIdx.x, lane = tid & 63, wid = tid >> 6;
  float s = 0.f, c = 0.f;
  for (int b = tid; b < LR_BLOCKS; b += 256) {
    s += partial[2 * b];
    c += partial[2 * b + 1];
  }
  #pragma unroll
  for (int off = 32; off; off >>= 1) {
    s += __shfl_xor(s, off);
    c += __shfl_xor(c, off);
  }
  if (lane == 0) { ssum[wid] = s; scnt[wid] = c; }
  __syncthreads();
  if (tid == 0) {
    float ts = ssum[0] + ssum[1] + ssum[2] + ssum[3];
    float tc = scnt[0] + scnt[1] + scnt[2] + scnt[3];
    out[0] = -0.1f * ts / fmaxf(tc, 1.0f);
  }
}

// ---------------------------------------------------------------------------
extern "C" void kernel_launch(void* const* d_in, const int* in_sizes, int n_in,
                              void* d_out, int out_size, void* d_ws, size_t ws_size,
                              hipStream_t stream)
{
  const float* X      = (const float*)d_in[0];
  const int*   labels = (const int*)d_in[1];
  const float* W1     = (const float*)d_in[2];
  const float* b1     = (const float*)d_in[3];
  const float* W2     = (const float*)d_in[4];
  const float* b2     = (const float*)d_in[5];
  float* out = (float*)d_out;

  const size_t NP = (size_t)NROWS * KPAD;
  const size_t WP = (size_t)KPAD * KPAD;
  short* Xh  = (short*)d_ws;
  short* Xl  = Xh + NP;
  short* Hh  = Xl + NP;
  short* Hl  = Hh + NP;
  short* FBp = Hl + NP;
  short* W1h = FBp + NP;
  short* W1l = W1h + WP;
  short* W2h = W1l + WP;
  short* W2l = W2h + WP;
  float* fpad = (float*)(W2l + WP);
  float* cs   = fpad + NP;
  float* S    = cs + (size_t)NCLS * KPAD;
  int*   cnt  = (int*)(S + NROWS);
  float* partial = (float*)(cnt + NCLS);

  size_t zbytes = ((size_t)NCLS * KPAD + NROWS + NCLS + 2 * LR_BLOCKS) * sizeof(float);
  hipMemsetAsync(cs, 0, zbytes, stream);

  conv_x <<<NROWS, 320, 0, stream>>>(X, Xh, Xl);
  conv_wt<<<KPAD,  320, 0, stream>>>(W1, W1h, W1l);
  conv_wt<<<KPAD,  320, 0, stream>>>(W2, W2h, W2l);

  dim3 pg(NROWS / 64, KPAD / 64);
  gemm_mfma3p<1, 1><<<pg, 64, 0, stream>>>(Xh, Xl, W1h, W1l, b1,
                                           nullptr, Hh, Hl);
  gemm_mfma3p<0, 0><<<pg, 64, 0, stream>>>(Hh, Hl, W2h, W2l, b2,
                                           fpad, nullptr, nullptr);

  normalize_count<<<NROWS / 4, 256, 0, stream>>>(fpad, FBp, labels, cnt);

  dim3 cg(NROWS / CSCHUNK, NCLS);
  class_sum_gather<<<cg, 320, 0, stream>>>(fpad, labels, cs);

  const int NTILE = NROWS / 128;                  // 64
  const int TRI   = NTILE * (NTILE + 1) / 2;      // 2080
  gram_s_mfma<<<TRI, 256, 0, stream>>>(FBp, S);

  loss_rows<<<LR_BLOCKS, 256, 0, stream>>>(fpad, labels, cnt, cs, S, partial);
  finalize<<<1, 256, 0, stream>>>(partial, out);
}